// Round 9
// baseline (6274.806 us; speedup 1.0000x reference)
//
#include <hip/hip_runtime.h>
#include <cstdint>

#define EPSF 1e-5f
#define NEG_BIG -1e30f

// ---- pos transform: x0 = (x + einsum) + pos_b ; einsum scalar path: seq c, mul+add, no fma ----
__global__ void k_pos(const float* __restrict__ x, const float* __restrict__ disc,
                      const float* __restrict__ pw, const float* __restrict__ pb,
                      float* __restrict__ x0){
  int n = blockIdx.x*256 + threadIdx.x;
  int o = blockIdx.y, b = blockIdx.z;
  float e = 0.f;
  #pragma unroll
  for(int c=0;c<6;c++) e = __fadd_rn(e, __fmul_rn(disc[((size_t)b*6+c)*1024+n], pw[o*6+c]));
  x0[((size_t)b*128+o)*1024+n] = __fadd_rn(__fadd_rn(x[((size_t)b*128 + o)*1024 + n], e), pb[o]);
}

// ---- squared norms: numpy reduce over middle axis = sequential c, mul rounded then add ----
__global__ void k_sqnorm(const float* __restrict__ xin, int xcoff, int xbstr,
                         float* __restrict__ sq){
  int n = blockIdx.x*256 + threadIdx.x;
  int b = blockIdx.y;
  const float* xp = xin + (size_t)b*xbstr + (size_t)xcoff*1024;
  float s=0.f;
  for(int c=0;c<128;c++){ float t = xp[c*1024+n]; s = __fadd_rn(s, __fmul_rn(t,t)); }
  sq[b*1024+n]=s;
}

// ---- top-12 insert (descending; stable) ----
__device__ __forceinline__ void ins12(float (&v)[12], int (&ii)[12], float key, int m){
  if(key > v[11]){
    #pragma unroll
    for(int j=11;j>0;j--){
      if(key > v[j-1]){ v[j]=v[j-1]; ii[j]=ii[j-1]; }
      else if(key > v[j]){ v[j]=key; ii[j]=m; }
    }
    if(key > v[0]){ v[0]=key; ii[0]=m; }
  }
}

// ---- kNN stage 1: einsum scalar path = strictly sequential c, mul+add (NO fma) ----
// key = ((2*dot - sq_n) - sq_m), tie-break lowest index
__global__ void __launch_bounds__(256,1) k_knn(const float* __restrict__ xin, int xcoff, int xbstr,
    const float* __restrict__ sq, float* __restrict__ pvals, int* __restrict__ pidx){
  __shared__ float xn[128][132];
  __shared__ float xm[128][132];
  const int tid = threadIdx.x;
  const int lane = tid & 63;
  const int q = tid >> 6;
  const int b = blockIdx.z, nt = blockIdx.x, mh = blockIdx.y;
  const int n0 = nt*128;
  const float* xp = xin + (size_t)b*xbstr + (size_t)xcoff*1024;
  for(int i=tid; i<128*32; i+=256){
    int c = i>>5, nn4 = (i&31)*4;
    float4 t = *(const float4*)&xp[c*1024 + n0 + nn4];
    xn[nn4+0][c]=t.x; xn[nn4+1][c]=t.y; xn[nn4+2][c]=t.z; xn[nn4+3][c]=t.w;
  }
  const float sqn0 = sq[b*1024 + n0 + lane];
  const float sqn1 = sq[b*1024 + n0 + 64 + lane];
  float vb[2][12]; int ib[2][12];
  #pragma unroll
  for(int j=0;j<12;j++){ vb[0][j]=NEG_BIG; vb[1][j]=NEG_BIG; ib[0][j]=0; ib[1][j]=0; }

  for(int mt=0; mt<4; mt++){
    const int m0 = mh*512 + mt*128;
    __syncthreads();
    for(int i=tid; i<128*32; i+=256){
      int c = i>>5, mm4 = (i&31)*4;
      float4 t = *(const float4*)&xp[c*1024 + m0 + mm4];
      xm[mm4+0][c]=t.x; xm[mm4+1][c]=t.y; xm[mm4+2][c]=t.z; xm[mm4+3][c]=t.w;
    }
    __syncthreads();
    float acc0[32], acc1[32];
    #pragma unroll
    for(int mm=0;mm<32;mm++){ acc0[mm]=0.f; acc1[mm]=0.f; }
    for(int cc=0; cc<128; cc+=16){
      float a0[16], a1[16];
      #pragma unroll
      for(int t=0;t<16;t++){ a0[t]=xn[lane][cc+t]; a1[t]=xn[lane+64][cc+t]; }
      #pragma unroll
      for(int mm=0;mm<32;mm++){
        const float* xr = &xm[q*32+mm][cc];
        #pragma unroll
        for(int t=0;t<16;t++){
          float bv = xr[t];
          acc0[mm] = __fadd_rn(acc0[mm], __fmul_rn(a0[t], bv));
          acc1[mm] = __fadd_rn(acc1[mm], __fmul_rn(a1[t], bv));
        }
      }
    }
    #pragma unroll
    for(int mm=0;mm<32;mm++){
      int m = m0 + q*32 + mm;
      float sqm = sq[b*1024 + m];
      float k0 = __fsub_rn(__fsub_rn(__fmul_rn(2.f,acc0[mm]), sqn0), sqm);
      float k1 = __fsub_rn(__fsub_rn(__fmul_rn(2.f,acc1[mm]), sqn1), sqm);
      ins12(vb[0], ib[0], k0, m);
      ins12(vb[1], ib[1], k1, m);
    }
  }
  __syncthreads();
  float* mv = &xn[0][0];
  int*   mi = (int*)&xm[0][0];
  const int STR = 49;
  #pragma unroll
  for(int j=0;j<12;j++){
    mv[lane*STR + q*12 + j]      = vb[0][j];
    mi[lane*STR + q*12 + j]      = ib[0][j];
    mv[(lane+64)*STR + q*12 + j] = vb[1][j];
    mi[(lane+64)*STR + q*12 + j] = ib[1][j];
  }
  __syncthreads();
  if(tid < 128){
    float* v48 = &mv[tid*STR];
    int*   i48 = &mi[tid*STR];
    size_t ob = ((size_t)(b*1024 + n0 + tid)*2 + mh)*12;
    for(int s=0;s<12;s++){
      float best = v48[0]; int bi=0;
      #pragma unroll
      for(int t2=1;t2<48;t2++){
        float vv=v48[t2];
        if(vv>best || (vv==best && i48[t2]<i48[bi])){ best=vv; bi=t2; }
      }
      pvals[ob+s]=best; pidx[ob+s]=i48[bi];
      v48[bi]=NEG_BIG;
    }
  }
}

// ---- merge halves -> final top-10 idx (tie-break lowest index) ----
__global__ void k_knn_merge(const float* __restrict__ pvals, const int* __restrict__ pidx,
                            int* __restrict__ idxo){
  int t = blockIdx.x*256 + threadIdx.x;
  float v[24]; int ii[24];
  #pragma unroll
  for(int s=0;s<24;s++){ v[s]=pvals[(size_t)t*24+s]; ii[s]=pidx[(size_t)t*24+s]; }
  #pragma unroll
  for(int s=0;s<10;s++){
    float best=v[0]; int bi=0;
    #pragma unroll
    for(int r=1;r<24;r++){
      float vv=v[r];
      if(vv>best || (vv==best && ii[r]<ii[bi])){ best=vv; bi=r; }
    }
    idxo[(size_t)t*10+s]=ii[bi]; v[bi]=NEG_BIG;
  }
}

// ---- EXACT edge y: einsum contiguous SIMD path = 4 lanes (c mod 4), mul+add, (A0+A1)+(A2+A3) ----
__global__ void __launch_bounds__(256,2) k_eexact(
    const float* __restrict__ xin, int xcoff, int xbstr,
    const int* __restrict__ idx, const float* __restrict__ W,
    const float* __restrict__ para, int poff, float* __restrict__ yb){
  __shared__ float Xn[2][128];
  __shared__ float F[20][128];
  __shared__ float Wt[32][128];
  const int tid = threadIdx.x;
  const int o = tid & 127, n2 = tid >> 7;
  const int b = blockIdx.y, n0 = blockIdx.x*2;
  const float p0 = para[poff], p1 = para[poff+1];
  const float* xp = xin + (size_t)b*xbstr + (size_t)xcoff*1024;
  { int n2s = tid>>7, c = tid&127; Xn[n2s][c] = xp[(size_t)c*1024 + n0 + n2s]; }
  __syncthreads();
  for(int i=tid; i<2560; i+=256){
    int col = i>>7, c = i&127;
    int n2s = (col>=10)?1:0, k = col - n2s*10;
    int j = idx[((size_t)b*1024 + n0 + n2s)*10 + k];
    F[col][c] = __fmul_rn(__fsub_rn(xp[(size_t)c*1024 + j], Xn[n2s][c]), p0);
  }
  float a4[10][4];
  #pragma unroll
  for(int k=0;k<10;k++){ a4[k][0]=0.f; a4[k][1]=0.f; a4[k][2]=0.f; a4[k][3]=0.f; }
  for(int kc=0;kc<8;kc++){
    __syncthreads();
    for(int i=tid;i<4096;i+=256){ int ol=i>>5, cc=i&31; Wt[cc][ol]=W[(size_t)ol*256 + kc*32 + cc]; }
    __syncthreads();
    if(kc<4){
      #pragma unroll
      for(int cc=0;cc<32;cc+=4){
        int c = kc*32+cc;
        float w0=Wt[cc][o], w1=Wt[cc+1][o], w2=Wt[cc+2][o], w3=Wt[cc+3][o];
        #pragma unroll
        for(int k=0;k<10;k++){
          float4 f4 = *(const float4*)&F[n2*10+k][c];
          a4[k][0]=__fadd_rn(a4[k][0], __fmul_rn(f4.x,w0));
          a4[k][1]=__fadd_rn(a4[k][1], __fmul_rn(f4.y,w1));
          a4[k][2]=__fadd_rn(a4[k][2], __fmul_rn(f4.z,w2));
          a4[k][3]=__fadd_rn(a4[k][3], __fmul_rn(f4.w,w3));
        }
      }
    } else {
      #pragma unroll
      for(int cc=0;cc<32;cc+=4){
        int c = kc*32+cc-128;
        float w0=Wt[cc][o], w1=Wt[cc+1][o], w2=Wt[cc+2][o], w3=Wt[cc+3][o];
        float4 x4 = *(const float4*)&Xn[n2][c];
        float f0=__fmul_rn(x4.x,p1), f1=__fmul_rn(x4.y,p1);
        float f2=__fmul_rn(x4.z,p1), f3=__fmul_rn(x4.w,p1);
        #pragma unroll
        for(int k=0;k<10;k++){
          a4[k][0]=__fadd_rn(a4[k][0], __fmul_rn(f0,w0));
          a4[k][1]=__fadd_rn(a4[k][1], __fmul_rn(f1,w1));
          a4[k][2]=__fadd_rn(a4[k][2], __fmul_rn(f2,w2));
          a4[k][3]=__fadd_rn(a4[k][3], __fmul_rn(f3,w3));
        }
      }
    }
  }
  size_t ybase = (((size_t)b*1024 + n0 + n2)*10)*128 + o;
  #pragma unroll
  for(int k=0;k<10;k++){
    float y = __fadd_rn(__fadd_rn(a4[k][0],a4[k][1]), __fadd_rn(a4[k][2],a4[k][3]));
    yb[ybase + (size_t)k*128] = y;
  }
}

// ---- BN pass 1: partial sums (deterministic slots) ----
__global__ void k_ystats_sum(const float* __restrict__ yb, float* __restrict__ epart){
  __shared__ float r1[256];
  const int tid=threadIdx.x, o=tid&127, part=tid>>7;
  const int nt=blockIdx.x, b=blockIdx.y;
  float s1=0.f;
  for(int jn=0;jn<32;jn++){
    int n = nt*64 + part*32 + jn;
    const float* yp = yb + (((size_t)b*1024+n)*10)*128 + o;
    #pragma unroll
    for(int k=0;k<10;k++) s1 = __fadd_rn(s1, yp[k*128]);
  }
  r1[tid]=s1; __syncthreads();
  if(part==0){
    int slot = b*16+nt;
    epart[(size_t)slot*512 + o] = __fadd_rn(r1[tid], r1[tid+128]);
  }
}

// ---- BN finalize mean: mv[o] = sum/N (rounded division, like np.mean) ----
__global__ void k_bnfin_mean(const float* __restrict__ epart, float* __restrict__ mv){
  int o = threadIdx.x;
  if(o<128){
    float s1=0.f;
    for(int s=0;s<256;s++) s1 += epart[(size_t)s*512 + o];
    mv[o] = __fdiv_rn(s1, 163840.f);
  }
}

// ---- BN pass 2: partial sums of (y-mean)^2 (two-pass var, like np.var) ----
__global__ void k_ystats_var(const float* __restrict__ yb, const float* __restrict__ mv,
                             float* __restrict__ epart){
  __shared__ float r2[256];
  const int tid=threadIdx.x, o=tid&127, part=tid>>7;
  const int nt=blockIdx.x, b=blockIdx.y;
  const float m = mv[o];
  float s2=0.f;
  for(int jn=0;jn<32;jn++){
    int n = nt*64 + part*32 + jn;
    const float* yp = yb + (((size_t)b*1024+n)*10)*128 + o;
    #pragma unroll
    for(int k=0;k<10;k++){ float t=__fsub_rn(yp[k*128],m); s2 = __fadd_rn(s2, __fmul_rn(t,t)); }
  }
  r2[tid]=s2; __syncthreads();
  if(part==0){
    int slot = b*16+nt;
    epart[(size_t)slot*512 + 256 + o] = __fadd_rn(r2[tid], r2[tid+128]);
  }
}

// ---- BN finalize var ----
__global__ void k_bnfin_var(const float* __restrict__ epart, float* __restrict__ mv){
  int o = threadIdx.x;
  if(o<128){
    float s2=0.f;
    for(int s=0;s<256;s++) s2 += epart[(size_t)s*512 + 256 + o];
    mv[256+o] = __fdiv_rn(s2, 163840.f);
  }
}

// ---- apply (no residual): exact bn ops + lrelu + max over k ----
__global__ void k_yapply(const float* __restrict__ yb, const float* __restrict__ mv,
    const float* __restrict__ g, const float* __restrict__ bbias,
    float* __restrict__ out){
  const int tid=threadIdx.x, o=tid&127, n2=tid>>7;
  const int b=blockIdx.y, n=blockIdx.x*2+n2;
  float m=mv[o], sd=__fsqrt_rn(__fadd_rn(mv[256+o],EPSF));
  float ga=g[o], be=bbias[o];
  const float* yp = yb + (((size_t)b*1024+n)*10)*128 + o;
  float mx=-3.4e38f;
  #pragma unroll
  for(int k=0;k<10;k++){
    float y=yp[k*128];
    float t=__fadd_rn(__fmul_rn(__fdiv_rn(__fsub_rn(y,m),sd),ga),be);
    t = (t>=0.f)? t : __fmul_rn(0.2f,t);
    mx = fmaxf(mx,t);
  }
  out[(size_t)b*655360 + (size_t)o*1024 + n] = mx;
}

// ---- apply with residual: 4-lane exact res-dot, bn(y)+lrelu+res, max over k ----
__global__ void __launch_bounds__(256,2) k_eapply_res(
    const float* __restrict__ xin, int xcoff, int xbstr,
    const int* __restrict__ idx, const float* __restrict__ RW,
    const float* __restrict__ para, int poff,
    const float* __restrict__ yb, const float* __restrict__ mv,
    const float* __restrict__ g, const float* __restrict__ bbias,
    float* __restrict__ out){
  __shared__ float Xn[2][128];
  __shared__ float F[20][128];
  __shared__ float Wt[32][128];
  const int tid = threadIdx.x;
  const int o = tid & 127, n2 = tid >> 7;
  const int b = blockIdx.y, n0 = blockIdx.x*2;
  const float p0 = para[poff], p1 = para[poff+1];
  const float* xp = xin + (size_t)b*xbstr + (size_t)xcoff*1024;
  { int n2s = tid>>7, c = tid&127; Xn[n2s][c] = xp[(size_t)c*1024 + n0 + n2s]; }
  __syncthreads();
  for(int i=tid; i<2560; i+=256){
    int col = i>>7, c = i&127;
    int n2s = (col>=10)?1:0, k = col - n2s*10;
    int j = idx[((size_t)b*1024 + n0 + n2s)*10 + k];
    F[col][c] = __fmul_rn(__fsub_rn(xp[(size_t)c*1024 + j], Xn[n2s][c]), p0);
  }
  float a4[10][4];
  #pragma unroll
  for(int k=0;k<10;k++){ a4[k][0]=0.f; a4[k][1]=0.f; a4[k][2]=0.f; a4[k][3]=0.f; }
  for(int kc=0;kc<8;kc++){
    __syncthreads();
    for(int i=tid;i<4096;i+=256){ int ol=i>>5, cc=i&31; Wt[cc][ol]=RW[(size_t)ol*256 + kc*32 + cc]; }
    __syncthreads();
    if(kc<4){
      #pragma unroll
      for(int cc=0;cc<32;cc+=4){
        int c = kc*32+cc;
        float w0=Wt[cc][o], w1=Wt[cc+1][o], w2=Wt[cc+2][o], w3=Wt[cc+3][o];
        #pragma unroll
        for(int k=0;k<10;k++){
          float4 f4 = *(const float4*)&F[n2*10+k][c];
          a4[k][0]=__fadd_rn(a4[k][0], __fmul_rn(f4.x,w0));
          a4[k][1]=__fadd_rn(a4[k][1], __fmul_rn(f4.y,w1));
          a4[k][2]=__fadd_rn(a4[k][2], __fmul_rn(f4.z,w2));
          a4[k][3]=__fadd_rn(a4[k][3], __fmul_rn(f4.w,w3));
        }
      }
    } else {
      #pragma unroll
      for(int cc=0;cc<32;cc+=4){
        int c = kc*32+cc-128;
        float w0=Wt[cc][o], w1=Wt[cc+1][o], w2=Wt[cc+2][o], w3=Wt[cc+3][o];
        float4 x4 = *(const float4*)&Xn[n2][c];
        float f0=__fmul_rn(x4.x,p1), f1=__fmul_rn(x4.y,p1);
        float f2=__fmul_rn(x4.z,p1), f3=__fmul_rn(x4.w,p1);
        #pragma unroll
        for(int k=0;k<10;k++){
          a4[k][0]=__fadd_rn(a4[k][0], __fmul_rn(f0,w0));
          a4[k][1]=__fadd_rn(a4[k][1], __fmul_rn(f1,w1));
          a4[k][2]=__fadd_rn(a4[k][2], __fmul_rn(f2,w2));
          a4[k][3]=__fadd_rn(a4[k][3], __fmul_rn(f3,w3));
        }
      }
    }
  }
  float m=mv[o], sd=__fsqrt_rn(__fadd_rn(mv[256+o],EPSF));
  float ga=g[o], be=bbias[o];
  const float* yp = yb + (((size_t)b*1024 + n0 + n2)*10)*128 + o;
  float mx=-3.4e38f;
  #pragma unroll
  for(int k=0;k<10;k++){
    float y=yp[k*128];
    float t=__fadd_rn(__fmul_rn(__fdiv_rn(__fsub_rn(y,m),sd),ga),be);
    t = (t>=0.f)? t : __fmul_rn(0.2f,t);
    float res = __fadd_rn(__fadd_rn(a4[k][0],a4[k][1]), __fadd_rn(a4[k][2],a4[k][3]));
    t = __fadd_rn(t, res);
    mx = fmaxf(mx,t);
  }
  out[(size_t)b*655360 + (size_t)o*1024 + n0 + n2] = mx;
}

// ---- generic fp32 GEMM (smooth consumers only) ----
__global__ void __launch_bounds__(256) k_gemm(const float* __restrict__ W, int ldw, int woff,
    const float* __restrict__ X, int xbstr, int xcoff,
    float* __restrict__ Out, int obstr, int Cin){
  __shared__ float Wt[16][68];
  __shared__ float Xt[16][64];
  const int b=blockIdx.z, o0=blockIdx.y*64, n0=blockIdx.x*64;
  const int tid=threadIdx.x, tn=tid&15, to=tid>>4;
  float acc[4][4];
  #pragma unroll
  for(int i=0;i<4;i++)
    #pragma unroll
    for(int j=0;j<4;j++) acc[i][j]=0.f;
  const float* Xp = X + (size_t)b*xbstr + (size_t)xcoff*1024 + n0;
  const float* Wp = W + woff;
  const int wo = tid>>2, wk=(tid&3)*4;
  const int xk = tid>>4, xn4=(tid&15)*4;
  for(int c0=0;c0<Cin;c0+=16){
    float4 wv = *(const float4*)&Wp[(size_t)(o0+wo)*ldw + c0 + wk];
    float4 xv = *(const float4*)&Xp[(size_t)(c0+xk)*1024 + xn4];
    Wt[wk+0][wo]=wv.x; Wt[wk+1][wo]=wv.y; Wt[wk+2][wo]=wv.z; Wt[wk+3][wo]=wv.w;
    *(float4*)&Xt[xk][xn4] = xv;
    __syncthreads();
    #pragma unroll
    for(int kk=0;kk<16;kk++){
      float av[4], bv[4];
      #pragma unroll
      for(int i=0;i<4;i++){ av[i]=Wt[kk][to*4+i]; bv[i]=Xt[kk][tn*4+i]; }
      #pragma unroll
      for(int i=0;i<4;i++)
        #pragma unroll
        for(int j=0;j<4;j++) acc[i][j]=fmaf(av[i],bv[j],acc[i][j]);
    }
    __syncthreads();
  }
  #pragma unroll
  for(int i=0;i<4;i++){
    float4 r; r.x=acc[i][0]; r.y=acc[i][1]; r.z=acc[i][2]; r.w=acc[i][3];
    *(float4*)&Out[(size_t)b*obstr + (size_t)(o0+to*4+i)*1024 + n0 + tn*4] = r;
  }
}

// ---- edge4 BN stats from factored u/v (smooth path) ----
__global__ void k_estats(const float* __restrict__ u, const float* __restrict__ v,
    const int* __restrict__ idx, const float* __restrict__ para, int poff,
    float* __restrict__ epart, int Cout){
  __shared__ float rs1[256], rs2[256];
  const int tid=threadIdx.x;
  const int b = blockIdx.y, n0 = blockIdx.x*64;
  const int o  = (Cout==128)? (tid&127) : tid;
  const int nl = (Cout==128)? (tid>>7) : 0;
  const int npt = 256/Cout;
  const float p0=para[poff], p1=para[poff+1];
  const float* ub = u + ((size_t)b*Cout + o)*1024;
  const float* vbp= v + ((size_t)b*Cout + o)*1024;
  float s1=0.f, s2=0.f;
  for(int jn=nl; jn<64; jn+=npt){
    int n = n0+jn;
    float un=ub[n], vn=vbp[n];
    float base = fmaf(p1,vn, -p0*un);
    const int* ip = idx + ((size_t)b*1024+n)*10;
    #pragma unroll
    for(int k2=0;k2<10;k2++){
      int j = ip[k2];
      float y = fmaf(p0, ub[j], base);
      s1 += y; s2 = fmaf(y,y,s2);
    }
  }
  rs1[tid]=s1; rs2[tid]=s2;
  __syncthreads();
  if(tid<Cout){
    float t1=rs1[tid], t2=rs2[tid];
    for(int p2=1;p2<npt;p2++){ t1+=rs1[tid+p2*Cout]; t2+=rs2[tid+p2*Cout]; }
    const int slot = blockIdx.y*16 + blockIdx.x;
    epart[(size_t)slot*512 + tid]       = t1;
    epart[(size_t)slot*512 + 256 + tid] = t2;
  }
}

__global__ void k_bnfin_edge(const float* __restrict__ epart,
    const float* __restrict__ g, const float* __restrict__ bbias, float inv_cnt,
    float* __restrict__ sc, float* __restrict__ sh, int C){
  int o = threadIdx.x;
  if(o<C){
    float s1=0.f, s2=0.f;
    for(int s=0;s<256;s++){
      s1 += epart[(size_t)s*512 + o];
      s2 += epart[(size_t)s*512 + 256 + o];
    }
    float mean = s1*inv_cnt;
    float var  = s2*inv_cnt - mean*mean;
    float sca = g[o]*rsqrtf(var+EPSF);
    sc[o]=sca; sh[o]=fmaf(-mean,sca,bbias[o]);
  }
}

__global__ void k_eapply(const float* __restrict__ u, const float* __restrict__ v,
    const int* __restrict__ idx, const float* __restrict__ para, int poff,
    const float* __restrict__ sc, const float* __restrict__ sh,
    float* __restrict__ out, int Cout){
  const int n = blockIdx.x*256+threadIdx.x;
  const int o = blockIdx.y, b = blockIdx.z;
  const float p0=para[poff], p1=para[poff+1];
  const float* ub = u + ((size_t)b*Cout+o)*1024;
  float un=ub[n], vn=v[((size_t)b*Cout+o)*1024+n];
  float base = fmaf(p1,vn,-p0*un);
  float s=sc[o], t=sh[o];
  const int* ip = idx + ((size_t)b*1024+n)*10;
  float m=-3.4e38f;
  #pragma unroll
  for(int k2=0;k2<10;k2++){
    int j=ip[k2];
    float y = fmaf(p0, ub[j], base);
    y = fmaf(y,s,t);
    y = (y>0.f)? y : 0.2f*y;
    m = fmaxf(m,y);
  }
  out[(size_t)b*655360 + (size_t)o*1024 + n] = m;
}

__global__ void k_cstats(const float* __restrict__ y5, float* __restrict__ cpart){
  __shared__ float r1[256], r2[256];
  const int o=blockIdx.x, b=blockIdx.y, tid=threadIdx.x;
  const float* yp = y5 + ((size_t)b*1024+o)*1024;
  float s1=0.f,s2=0.f;
  for(int n=tid;n<1024;n+=256){ float y=yp[n]; s1+=y; s2=fmaf(y,y,s2); }
  r1[tid]=s1; r2[tid]=s2; __syncthreads();
  for(int st=128; st>0; st>>=1){ if(tid<st){ r1[tid]+=r1[tid+st]; r2[tid]+=r2[tid+st]; } __syncthreads(); }
  if(tid==0){ cpart[(size_t)b*2048 + o] = r1[0]; cpart[(size_t)b*2048 + 1024 + o] = r2[0]; }
}

__global__ void k_bnfin5(const float* __restrict__ cpart,
    const float* __restrict__ g, const float* __restrict__ bbias, float inv_cnt,
    float* __restrict__ sc, float* __restrict__ sh){
  int o = blockIdx.x*256+threadIdx.x;
  float s1=0.f, s2=0.f;
  #pragma unroll
  for(int b=0;b<16;b++){
    s1 += cpart[(size_t)b*2048 + o];
    s2 += cpart[(size_t)b*2048 + 1024 + o];
  }
  float mean = s1*inv_cnt;
  float var  = s2*inv_cnt - mean*mean;
  float sca = g[o]*rsqrtf(var+EPSF);
  sc[o]=sca; sh[o]=fmaf(-mean,sca,bbias[o]);
}

__global__ void k_pool(const float* __restrict__ y5, const float* __restrict__ sc,
    const float* __restrict__ sh, float* __restrict__ p){
  __shared__ float r1[256], r2[256];
  const int o=blockIdx.x, b=blockIdx.y, tid=threadIdx.x;
  const float* yp = y5 + ((size_t)b*1024+o)*1024;
  float s=sc[o], t=sh[o];
  float mx=-3.4e38f, sm=0.f;
  for(int n=tid;n<1024;n+=256){
    float y=fmaf(yp[n],s,t);
    y=(y>0.f)?y:0.2f*y;
    mx=fmaxf(mx,y); sm+=y;
  }
  r1[tid]=mx; r2[tid]=sm; __syncthreads();
  for(int st=128; st>0; st>>=1){ if(tid<st){ r1[tid]=fmaxf(r1[tid],r1[tid+st]); r2[tid]+=r2[tid+st]; } __syncthreads(); }
  if(tid==0){ p[(size_t)b*2048+o]=r1[0]; p[(size_t)b*2048+1024+o]=r2[0]*(1.f/1024.f); }
}

__global__ void k_lin(const float* __restrict__ In, const float* __restrict__ W,
    const float* __restrict__ g, const float* __restrict__ bbias,
    float* __restrict__ out, int Cin, int Jtot){
  __shared__ float zb[16];
  __shared__ float sscale, sshift;
  const int j=blockIdx.x, tid=threadIdx.x;
  const int bi=tid>>4, part=tid&15;
  const int chunk=Cin>>4;
  const float* ip = In + (size_t)bi*Cin + part*chunk;
  const float* wp = W + (size_t)j*Cin + part*chunk;
  float s=0.f;
  for(int i=0;i<chunk;i++) s=fmaf(ip[i],wp[i],s);
  #pragma unroll
  for(int off=8;off>=1;off>>=1) s += __shfl_xor(s,off,16);
  if(part==0) zb[bi]=s;
  __syncthreads();
  if(tid==0){
    float m=0.f;
    #pragma unroll
    for(int i=0;i<16;i++) m+=zb[i];
    m*=0.0625f;
    float vv=0.f;
    #pragma unroll
    for(int i=0;i<16;i++){ float d=zb[i]-m; vv=fmaf(d,d,vv); }
    vv*=0.0625f;
    float sc=g[j]*rsqrtf(vv+EPSF);
    sscale=sc; sshift=fmaf(-m,sc,bbias[j]);
  }
  __syncthreads();
  if(tid<16){
    float y=fmaf(zb[tid],sscale,sshift);
    y=(y>0.f)?y:0.2f*y;
    out[(size_t)tid*Jtot + j]=y;
  }
}

extern "C" void kernel_launch(void* const* d_in, const int* in_sizes, int n_in,
                              void* d_out, int out_size, void* d_ws, size_t ws_size,
                              hipStream_t stream){
  const float* disc=(const float*)d_in[0];
  const float* x   =(const float*)d_in[1];
  const float* pos_w=(const float*)d_in[3];
  const float* pos_b=(const float*)d_in[4];
  const float* para=(const float*)d_in[5];
  const float* w1=(const float*)d_in[6];
  const float* g1=(const float*)d_in[7];
  const float* b1=(const float*)d_in[8];
  const float* r1w=(const float*)d_in[9];
  const float* w2=(const float*)d_in[10];
  const float* g2=(const float*)d_in[11];
  const float* b2=(const float*)d_in[12];
  const float* w3=(const float*)d_in[13];
  const float* g3=(const float*)d_in[14];
  const float* b3=(const float*)d_in[15];
  const float* r3w=(const float*)d_in[16];
  const float* w4=(const float*)d_in[17];
  const float* g4=(const float*)d_in[18];
  const float* b4=(const float*)d_in[19];
  const float* w5=(const float*)d_in[20];
  const float* g5=(const float*)d_in[21];
  const float* b5=(const float*)d_in[22];
  const float* l1w=(const float*)d_in[23];
  const float* g6=(const float*)d_in[24];
  const float* b6=(const float*)d_in[25];
  const float* l2w=(const float*)d_in[26];
  const float* g7=(const float*)d_in[27];
  const float* b7=(const float*)d_in[28];

  float* ws=(float*)d_ws;
  float* x0 = ws;                     // 2,097,152
  float* xc = x0 + 2097152;           // 10,485,760
  float* yb = xc + 10485760;          // 20,971,520 (16*1024*10*128)
  float* u  = yb;                     // edge4 only
  float* v  = yb + 4194304;           // edge4 only
  float* y5 = yb;                     // conv5 out (aliases, after edges)
  float* tail = yb + 20971520;
  float* sq = tail;                   // 16,384
  float* pv = sq + 16384;             // 393,216
  int*   pi = (int*)(pv + 393216);    // 393,216
  int*   idx= pi + 393216;            // 163,840
  float* epart = (float*)(idx + 163840); // 131,072
  float* cpart = epart + 131072;      // 32,768
  float* scsh  = cpart + 32768;       // 4,096
  float* p  = scsh + 4096;            // 32,768
  float* h1 = p + 32768;              // 8,192

  k_pos<<<dim3(4,128,16),256,0,stream>>>(x,disc,pos_w,pos_b,x0);

  auto knn=[&](const float* xin, int xcoff, int xbstr){
    k_sqnorm<<<dim3(4,16),256,0,stream>>>(xin,xcoff,xbstr,sq);
    k_knn<<<dim3(8,2,16),256,0,stream>>>(xin,xcoff,xbstr,sq,pv,pi);
    k_knn_merge<<<dim3(64),256,0,stream>>>(pv,pi,idx);
  };

  auto edge_exact=[&](const float* xin, int xcoff, int xbstr,
                      const float* w, const float* resw,
                      const float* g, const float* bbias, int poff, int cbase, int blk){
    knn(xin,xcoff,xbstr);
    k_eexact<<<dim3(512,16),256,0,stream>>>(xin,xcoff,xbstr, idx, w, para,poff, yb);
    float* mv = scsh + blk*512;
    k_ystats_sum<<<dim3(16,16),256,0,stream>>>(yb, epart);
    k_bnfin_mean<<<1,256,0,stream>>>(epart, mv);
    k_ystats_var<<<dim3(16,16),256,0,stream>>>(yb, mv, epart);
    k_bnfin_var<<<1,256,0,stream>>>(epart, mv);
    if(resw)
      k_eapply_res<<<dim3(512,16),256,0,stream>>>(xin,xcoff,xbstr, idx, resw, para,poff,
                                                  yb, mv, g,bbias, xc + (size_t)cbase*1024);
    else
      k_yapply<<<dim3(512,16),256,0,stream>>>(yb, mv, g,bbias, xc + (size_t)cbase*1024);
  };

  edge_exact(x0,   0, 131072, w1, r1w,    g1, b1, 0,   0, 0);
  edge_exact(xc,   0, 655360, w2, nullptr,g2, b2, 4, 128, 1);
  edge_exact(xc, 128, 655360, w3, r3w,    g3, b3, 8, 256, 2);

  // edge 4 (smooth consumers only): fast factored path
  {
    knn(xc, 256, 655360);
    dim3 gg(16,4,16);
    k_gemm<<<gg,256,0,stream>>>(w4,256,0,  xc,655360,256, u, 262144, 128);
    k_gemm<<<gg,256,0,stream>>>(w4,256,128,xc,655360,256, v, 262144, 128);
    float* scb = scsh + 3*512;
    float* shb = scb + 256;
    k_estats<<<dim3(16,16),256,0,stream>>>(u,v,idx,para,12,epart,256);
    k_bnfin_edge<<<1,256,0,stream>>>(epart,g4,b4,1.f/163840.f,scb,shb,256);
    k_eapply<<<dim3(4,256,16),256,0,stream>>>(u,v,idx,para,12,scb,shb,
                                              xc + (size_t)384*1024, 256);
  }

  float* sc5 = scsh + 2048;
  float* sh5 = sc5 + 1024;
  k_gemm<<<dim3(16,16,16),256,0,stream>>>(w5,640,0, xc,655360,0, y5,1048576, 640);
  k_cstats<<<dim3(1024,16),256,0,stream>>>(y5,cpart);
  k_bnfin5<<<dim3(4),256,0,stream>>>(cpart,g5,b5,1.f/16384.f,sc5,sh5);
  k_pool<<<dim3(1024,16),256,0,stream>>>(y5,sc5,sh5,p);
  k_lin<<<512,256,0,stream>>>(p,l1w,g6,b6,h1,2048,512);
  k_lin<<<256,256,0,stream>>>(h1,l2w,g7,b7,(float*)d_out,512,256);
}

// Round 10
// 4713.290 us; speedup vs baseline: 1.3313x; 1.3313x over previous
//
#include <hip/hip_runtime.h>
#include <cstdint>

#define EPSF 1e-5f
#define NEG_BIG -1e30f

// ---- pos transform: x0 = (x + einsum) + pos_b ; einsum scalar path: seq c, mul+add, no fma ----
__global__ void k_pos(const float* __restrict__ x, const float* __restrict__ disc,
                      const float* __restrict__ pw, const float* __restrict__ pb,
                      float* __restrict__ x0){
  int n = blockIdx.x*256 + threadIdx.x;
  int o = blockIdx.y, b = blockIdx.z;
  float e = 0.f;
  #pragma unroll
  for(int c=0;c<6;c++) e = __fadd_rn(e, __fmul_rn(disc[((size_t)b*6+c)*1024+n], pw[o*6+c]));
  x0[((size_t)b*128+o)*1024+n] = __fadd_rn(__fadd_rn(x[((size_t)b*128 + o)*1024 + n], e), pb[o]);
}

// ---- squared norms: sequential c, mul rounded then add ----
__global__ void k_sqnorm(const float* __restrict__ xin, int xcoff, int xbstr,
                         float* __restrict__ sq){
  int n = blockIdx.x*256 + threadIdx.x;
  int b = blockIdx.y;
  const float* xp = xin + (size_t)b*xbstr + (size_t)xcoff*1024;
  float s=0.f;
  for(int c=0;c<128;c++){ float t = xp[c*1024+n]; s = __fadd_rn(s, __fmul_rn(t,t)); }
  sq[b*1024+n]=s;
}

// ---- top-12 insert (descending; stable) ----
__device__ __forceinline__ void ins12(float (&v)[12], int (&ii)[12], float key, int m){
  if(key > v[11]){
    #pragma unroll
    for(int j=11;j>0;j--){
      if(key > v[j-1]){ v[j]=v[j-1]; ii[j]=ii[j-1]; }
      else if(key > v[j]){ v[j]=key; ii[j]=m; }
    }
    if(key > v[0]){ v[0]=key; ii[0]=m; }
  }
}

// ---- kNN stage 1: 64n x 64m tiles, pad-129 rows (conflict-free), 2 blocks/CU ----
// numerics identical: per (n,m) single accumulator, strictly sequential c, mul+add (NO fma)
__global__ void __launch_bounds__(256,2) k_knn(const float* __restrict__ xin, int xcoff, int xbstr,
    const float* __restrict__ sq, float* __restrict__ pvals, int* __restrict__ pidx){
  __shared__ float xn[64][129];
  __shared__ float xm[64][129];
  const int tid = threadIdx.x;
  const int lane = tid & 63;
  const int q = tid >> 6;           // m-splitter 0..3 (16 m each per 64-m tile)
  const int b = blockIdx.z, nt = blockIdx.x, mh = blockIdx.y;
  const int n0 = nt*64;
  const float* xp = xin + (size_t)b*xbstr + (size_t)xcoff*1024;
  // load xn tile: 64 n x 128 c (float4 along n)
  for(int i=tid; i<2048; i+=256){
    int c = i>>4, nn4 = (i&15)*4;
    float4 t = *(const float4*)&xp[c*1024 + n0 + nn4];
    xn[nn4+0][c]=t.x; xn[nn4+1][c]=t.y; xn[nn4+2][c]=t.z; xn[nn4+3][c]=t.w;
  }
  const float sqn = sq[b*1024 + n0 + lane];
  float vb[12]; int ib[12];
  #pragma unroll
  for(int j=0;j<12;j++){ vb[j]=NEG_BIG; ib[j]=0; }

  for(int mt=0; mt<8; mt++){
    const int m0 = mh*512 + mt*64;
    __syncthreads();
    for(int i=tid; i<2048; i+=256){
      int c = i>>4, mm4 = (i&15)*4;
      float4 t = *(const float4*)&xp[c*1024 + m0 + mm4];
      xm[mm4+0][c]=t.x; xm[mm4+1][c]=t.y; xm[mm4+2][c]=t.z; xm[mm4+3][c]=t.w;
    }
    __syncthreads();
    float acc[16];
    #pragma unroll
    for(int mm=0;mm<16;mm++) acc[mm]=0.f;
    for(int cc=0; cc<128; cc+=16){
      float a0[16];
      #pragma unroll
      for(int t=0;t<16;t++) a0[t]=xn[lane][cc+t];
      #pragma unroll
      for(int mm=0;mm<16;mm++){
        const float* xr = &xm[q*16+mm][cc];
        #pragma unroll
        for(int t=0;t<16;t++)
          acc[mm] = __fadd_rn(acc[mm], __fmul_rn(a0[t], xr[t]));
      }
    }
    #pragma unroll
    for(int mm=0;mm<16;mm++){
      int m = m0 + q*16 + mm;
      float sqm = sq[b*1024 + m];
      float k0 = __fsub_rn(__fsub_rn(__fmul_rn(2.f,acc[mm]), sqn), sqm);
      ins12(vb, ib, k0, m);
    }
  }
  __syncthreads();
  // merge 4 q-lists per n: top-12 of 48, tie-break lowest index
  float* mv = &xn[0][0];
  int*   mi = (int*)&xm[0][0];
  const int STR = 49;
  #pragma unroll
  for(int j=0;j<12;j++){
    mv[lane*STR + q*12 + j] = vb[j];
    mi[lane*STR + q*12 + j] = ib[j];
  }
  __syncthreads();
  if(tid < 64){
    float* v48 = &mv[tid*STR];
    int*   i48 = &mi[tid*STR];
    size_t ob = ((size_t)(b*1024 + n0 + tid)*2 + mh)*12;
    for(int s=0;s<12;s++){
      float best = v48[0]; int bi=0;
      #pragma unroll
      for(int t2=1;t2<48;t2++){
        float vv=v48[t2];
        if(vv>best || (vv==best && i48[t2]<i48[bi])){ best=vv; bi=t2; }
      }
      pvals[ob+s]=best; pidx[ob+s]=i48[bi];
      v48[bi]=NEG_BIG;
    }
  }
}

// ---- merge halves -> final top-10 idx (tie-break lowest index) ----
__global__ void k_knn_merge(const float* __restrict__ pvals, const int* __restrict__ pidx,
                            int* __restrict__ idxo){
  int t = blockIdx.x*256 + threadIdx.x;
  float v[24]; int ii[24];
  #pragma unroll
  for(int s=0;s<24;s++){ v[s]=pvals[(size_t)t*24+s]; ii[s]=pidx[(size_t)t*24+s]; }
  #pragma unroll
  for(int s=0;s<10;s++){
    float best=v[0]; int bi=0;
    #pragma unroll
    for(int r=1;r<24;r++){
      float vv=v[r];
      if(vv>best || (vv==best && ii[r]<ii[bi])){ best=vv; bi=r; }
    }
    idxo[(size_t)t*10+s]=ii[bi]; v[bi]=NEG_BIG;
  }
}

// ---- EXACT edge y: 4-lane accumulators, mul+add, (A0+A1)+(A2+A3); Wt padded to 129 ----
__global__ void __launch_bounds__(256,2) k_eexact(
    const float* __restrict__ xin, int xcoff, int xbstr,
    const int* __restrict__ idx, const float* __restrict__ W,
    const float* __restrict__ para, int poff, float* __restrict__ yb){
  __shared__ float Xn[2][128];
  __shared__ float F[20][128];
  __shared__ float Wt[32][129];
  const int tid = threadIdx.x;
  const int o = tid & 127, n2 = tid >> 7;
  const int b = blockIdx.y, n0 = blockIdx.x*2;
  const float p0 = para[poff], p1 = para[poff+1];
  const float* xp = xin + (size_t)b*xbstr + (size_t)xcoff*1024;
  { int n2s = tid>>7, c = tid&127; Xn[n2s][c] = xp[(size_t)c*1024 + n0 + n2s]; }
  __syncthreads();
  for(int i=tid; i<2560; i+=256){
    int col = i>>7, c = i&127;
    int n2s = (col>=10)?1:0, k = col - n2s*10;
    int j = idx[((size_t)b*1024 + n0 + n2s)*10 + k];
    F[col][c] = __fmul_rn(__fsub_rn(xp[(size_t)c*1024 + j], Xn[n2s][c]), p0);
  }
  float a4[10][4];
  #pragma unroll
  for(int k=0;k<10;k++){ a4[k][0]=0.f; a4[k][1]=0.f; a4[k][2]=0.f; a4[k][3]=0.f; }
  for(int kc=0;kc<8;kc++){
    __syncthreads();
    for(int i=tid;i<4096;i+=256){ int ol=i>>5, cc=i&31; Wt[cc][ol]=W[(size_t)ol*256 + kc*32 + cc]; }
    __syncthreads();
    if(kc<4){
      #pragma unroll
      for(int cc=0;cc<32;cc+=4){
        int c = kc*32+cc;
        float w0=Wt[cc][o], w1=Wt[cc+1][o], w2=Wt[cc+2][o], w3=Wt[cc+3][o];
        #pragma unroll
        for(int k=0;k<10;k++){
          float4 f4 = *(const float4*)&F[n2*10+k][c];
          a4[k][0]=__fadd_rn(a4[k][0], __fmul_rn(f4.x,w0));
          a4[k][1]=__fadd_rn(a4[k][1], __fmul_rn(f4.y,w1));
          a4[k][2]=__fadd_rn(a4[k][2], __fmul_rn(f4.z,w2));
          a4[k][3]=__fadd_rn(a4[k][3], __fmul_rn(f4.w,w3));
        }
      }
    } else {
      #pragma unroll
      for(int cc=0;cc<32;cc+=4){
        int c = kc*32+cc-128;
        float w0=Wt[cc][o], w1=Wt[cc+1][o], w2=Wt[cc+2][o], w3=Wt[cc+3][o];
        float4 x4 = *(const float4*)&Xn[n2][c];
        float f0=__fmul_rn(x4.x,p1), f1=__fmul_rn(x4.y,p1);
        float f2=__fmul_rn(x4.z,p1), f3=__fmul_rn(x4.w,p1);
        #pragma unroll
        for(int k=0;k<10;k++){
          a4[k][0]=__fadd_rn(a4[k][0], __fmul_rn(f0,w0));
          a4[k][1]=__fadd_rn(a4[k][1], __fmul_rn(f1,w1));
          a4[k][2]=__fadd_rn(a4[k][2], __fmul_rn(f2,w2));
          a4[k][3]=__fadd_rn(a4[k][3], __fmul_rn(f3,w3));
        }
      }
    }
  }
  size_t ybase = (((size_t)b*1024 + n0 + n2)*10)*128 + o;
  #pragma unroll
  for(int k=0;k<10;k++){
    float y = __fadd_rn(__fadd_rn(a4[k][0],a4[k][1]), __fadd_rn(a4[k][2],a4[k][3]));
    yb[ybase + (size_t)k*128] = y;
  }
}

// ---- BN pass 1: partial sums (deterministic slots) ----
__global__ void k_ystats_sum(const float* __restrict__ yb, float* __restrict__ epart){
  __shared__ float r1[256];
  const int tid=threadIdx.x, o=tid&127, part=tid>>7;
  const int nt=blockIdx.x, b=blockIdx.y;
  float s1=0.f;
  for(int jn=0;jn<32;jn++){
    int n = nt*64 + part*32 + jn;
    const float* yp = yb + (((size_t)b*1024+n)*10)*128 + o;
    #pragma unroll
    for(int k=0;k<10;k++) s1 = __fadd_rn(s1, yp[k*128]);
  }
  r1[tid]=s1; __syncthreads();
  if(part==0){
    int slot = b*16+nt;
    epart[(size_t)slot*512 + o] = __fadd_rn(r1[tid], r1[tid+128]);
  }
}

// ---- BN finalize mean ----
__global__ void k_bnfin_mean(const float* __restrict__ epart, float* __restrict__ mv){
  int o = threadIdx.x;
  if(o<128){
    float s1=0.f;
    for(int s=0;s<256;s++) s1 += epart[(size_t)s*512 + o];
    mv[o] = __fdiv_rn(s1, 163840.f);
  }
}

// ---- BN pass 2: partial sums of (y-mean)^2 ----
__global__ void k_ystats_var(const float* __restrict__ yb, const float* __restrict__ mv,
                             float* __restrict__ epart){
  __shared__ float r2[256];
  const int tid=threadIdx.x, o=tid&127, part=tid>>7;
  const int nt=blockIdx.x, b=blockIdx.y;
  const float m = mv[o];
  float s2=0.f;
  for(int jn=0;jn<32;jn++){
    int n = nt*64 + part*32 + jn;
    const float* yp = yb + (((size_t)b*1024+n)*10)*128 + o;
    #pragma unroll
    for(int k=0;k<10;k++){ float t=__fsub_rn(yp[k*128],m); s2 = __fadd_rn(s2, __fmul_rn(t,t)); }
  }
  r2[tid]=s2; __syncthreads();
  if(part==0){
    int slot = b*16+nt;
    epart[(size_t)slot*512 + 256 + o] = __fadd_rn(r2[tid], r2[tid+128]);
  }
}

// ---- BN finalize var ----
__global__ void k_bnfin_var(const float* __restrict__ epart, float* __restrict__ mv){
  int o = threadIdx.x;
  if(o<128){
    float s2=0.f;
    for(int s=0;s<256;s++) s2 += epart[(size_t)s*512 + 256 + o];
    mv[256+o] = __fdiv_rn(s2, 163840.f);
  }
}

// ---- apply (no residual): exact bn ops + lrelu + max over k ----
__global__ void k_yapply(const float* __restrict__ yb, const float* __restrict__ mv,
    const float* __restrict__ g, const float* __restrict__ bbias,
    float* __restrict__ out){
  const int tid=threadIdx.x, o=tid&127, n2=tid>>7;
  const int b=blockIdx.y, n=blockIdx.x*2+n2;
  float m=mv[o], sd=__fsqrt_rn(__fadd_rn(mv[256+o],EPSF));
  float ga=g[o], be=bbias[o];
  const float* yp = yb + (((size_t)b*1024+n)*10)*128 + o;
  float mx=-3.4e38f;
  #pragma unroll
  for(int k=0;k<10;k++){
    float y=yp[k*128];
    float t=__fadd_rn(__fmul_rn(__fdiv_rn(__fsub_rn(y,m),sd),ga),be);
    t = (t>=0.f)? t : __fmul_rn(0.2f,t);
    mx = fmaxf(mx,t);
  }
  out[(size_t)b*655360 + (size_t)o*1024 + n] = mx;
}

// ---- apply with residual: 4-lane exact res-dot (Wt padded), bn(y)+lrelu+res, max ----
__global__ void __launch_bounds__(256,2) k_eapply_res(
    const float* __restrict__ xin, int xcoff, int xbstr,
    const int* __restrict__ idx, const float* __restrict__ RW,
    const float* __restrict__ para, int poff,
    const float* __restrict__ yb, const float* __restrict__ mv,
    const float* __restrict__ g, const float* __restrict__ bbias,
    float* __restrict__ out){
  __shared__ float Xn[2][128];
  __shared__ float F[20][128];
  __shared__ float Wt[32][129];
  const int tid = threadIdx.x;
  const int o = tid & 127, n2 = tid >> 7;
  const int b = blockIdx.y, n0 = blockIdx.x*2;
  const float p0 = para[poff], p1 = para[poff+1];
  const float* xp = xin + (size_t)b*xbstr + (size_t)xcoff*1024;
  { int n2s = tid>>7, c = tid&127; Xn[n2s][c] = xp[(size_t)c*1024 + n0 + n2s]; }
  __syncthreads();
  for(int i=tid; i<2560; i+=256){
    int col = i>>7, c = i&127;
    int n2s = (col>=10)?1:0, k = col - n2s*10;
    int j = idx[((size_t)b*1024 + n0 + n2s)*10 + k];
    F[col][c] = __fmul_rn(__fsub_rn(xp[(size_t)c*1024 + j], Xn[n2s][c]), p0);
  }
  float a4[10][4];
  #pragma unroll
  for(int k=0;k<10;k++){ a4[k][0]=0.f; a4[k][1]=0.f; a4[k][2]=0.f; a4[k][3]=0.f; }
  for(int kc=0;kc<8;kc++){
    __syncthreads();
    for(int i=tid;i<4096;i+=256){ int ol=i>>5, cc=i&31; Wt[cc][ol]=RW[(size_t)ol*256 + kc*32 + cc]; }
    __syncthreads();
    if(kc<4){
      #pragma unroll
      for(int cc=0;cc<32;cc+=4){
        int c = kc*32+cc;
        float w0=Wt[cc][o], w1=Wt[cc+1][o], w2=Wt[cc+2][o], w3=Wt[cc+3][o];
        #pragma unroll
        for(int k=0;k<10;k++){
          float4 f4 = *(const float4*)&F[n2*10+k][c];
          a4[k][0]=__fadd_rn(a4[k][0], __fmul_rn(f4.x,w0));
          a4[k][1]=__fadd_rn(a4[k][1], __fmul_rn(f4.y,w1));
          a4[k][2]=__fadd_rn(a4[k][2], __fmul_rn(f4.z,w2));
          a4[k][3]=__fadd_rn(a4[k][3], __fmul_rn(f4.w,w3));
        }
      }
    } else {
      #pragma unroll
      for(int cc=0;cc<32;cc+=4){
        int c = kc*32+cc-128;
        float w0=Wt[cc][o], w1=Wt[cc+1][o], w2=Wt[cc+2][o], w3=Wt[cc+3][o];
        float4 x4 = *(const float4*)&Xn[n2][c];
        float f0=__fmul_rn(x4.x,p1), f1=__fmul_rn(x4.y,p1);
        float f2=__fmul_rn(x4.z,p1), f3=__fmul_rn(x4.w,p1);
        #pragma unroll
        for(int k=0;k<10;k++){
          a4[k][0]=__fadd_rn(a4[k][0], __fmul_rn(f0,w0));
          a4[k][1]=__fadd_rn(a4[k][1], __fmul_rn(f1,w1));
          a4[k][2]=__fadd_rn(a4[k][2], __fmul_rn(f2,w2));
          a4[k][3]=__fadd_rn(a4[k][3], __fmul_rn(f3,w3));
        }
      }
    }
  }
  float m=mv[o], sd=__fsqrt_rn(__fadd_rn(mv[256+o],EPSF));
  float ga=g[o], be=bbias[o];
  const float* yp = yb + (((size_t)b*1024 + n0 + n2)*10)*128 + o;
  float mx=-3.4e38f;
  #pragma unroll
  for(int k=0;k<10;k++){
    float y=yp[k*128];
    float t=__fadd_rn(__fmul_rn(__fdiv_rn(__fsub_rn(y,m),sd),ga),be);
    t = (t>=0.f)? t : __fmul_rn(0.2f,t);
    float res = __fadd_rn(__fadd_rn(a4[k][0],a4[k][1]), __fadd_rn(a4[k][2],a4[k][3]));
    t = __fadd_rn(t, res);
    mx = fmaxf(mx,t);
  }
  out[(size_t)b*655360 + (size_t)o*1024 + n0 + n2] = mx;
}

// ---- generic fp32 GEMM (smooth consumers only) ----
__global__ void __launch_bounds__(256) k_gemm(const float* __restrict__ W, int ldw, int woff,
    const float* __restrict__ X, int xbstr, int xcoff,
    float* __restrict__ Out, int obstr, int Cin){
  __shared__ float Wt[16][68];
  __shared__ float Xt[16][64];
  const int b=blockIdx.z, o0=blockIdx.y*64, n0=blockIdx.x*64;
  const int tid=threadIdx.x, tn=tid&15, to=tid>>4;
  float acc[4][4];
  #pragma unroll
  for(int i=0;i<4;i++)
    #pragma unroll
    for(int j=0;j<4;j++) acc[i][j]=0.f;
  const float* Xp = X + (size_t)b*xbstr + (size_t)xcoff*1024 + n0;
  const float* Wp = W + woff;
  const int wo = tid>>2, wk=(tid&3)*4;
  const int xk = tid>>4, xn4=(tid&15)*4;
  for(int c0=0;c0<Cin;c0+=16){
    float4 wv = *(const float4*)&Wp[(size_t)(o0+wo)*ldw + c0 + wk];
    float4 xv = *(const float4*)&Xp[(size_t)(c0+xk)*1024 + xn4];
    Wt[wk+0][wo]=wv.x; Wt[wk+1][wo]=wv.y; Wt[wk+2][wo]=wv.z; Wt[wk+3][wo]=wv.w;
    *(float4*)&Xt[xk][xn4] = xv;
    __syncthreads();
    #pragma unroll
    for(int kk=0;kk<16;kk++){
      float av[4], bv[4];
      #pragma unroll
      for(int i=0;i<4;i++){ av[i]=Wt[kk][to*4+i]; bv[i]=Xt[kk][tn*4+i]; }
      #pragma unroll
      for(int i=0;i<4;i++)
        #pragma unroll
        for(int j=0;j<4;j++) acc[i][j]=fmaf(av[i],bv[j],acc[i][j]);
    }
    __syncthreads();
  }
  #pragma unroll
  for(int i=0;i<4;i++){
    float4 r; r.x=acc[i][0]; r.y=acc[i][1]; r.z=acc[i][2]; r.w=acc[i][3];
    *(float4*)&Out[(size_t)b*obstr + (size_t)(o0+to*4+i)*1024 + n0 + tn*4] = r;
  }
}

// ---- edge4 BN stats from factored u/v (smooth path) ----
__global__ void k_estats(const float* __restrict__ u, const float* __restrict__ v,
    const int* __restrict__ idx, const float* __restrict__ para, int poff,
    float* __restrict__ epart, int Cout){
  __shared__ float rs1[256], rs2[256];
  const int tid=threadIdx.x;
  const int b = blockIdx.y, n0 = blockIdx.x*64;
  const int o  = (Cout==128)? (tid&127) : tid;
  const int nl = (Cout==128)? (tid>>7) : 0;
  const int npt = 256/Cout;
  const float p0=para[poff], p1=para[poff+1];
  const float* ub = u + ((size_t)b*Cout + o)*1024;
  const float* vbp= v + ((size_t)b*Cout + o)*1024;
  float s1=0.f, s2=0.f;
  for(int jn=nl; jn<64; jn+=npt){
    int n = n0+jn;
    float un=ub[n], vn=vbp[n];
    float base = fmaf(p1,vn, -p0*un);
    const int* ip = idx + ((size_t)b*1024+n)*10;
    #pragma unroll
    for(int k2=0;k2<10;k2++){
      int j = ip[k2];
      float y = fmaf(p0, ub[j], base);
      s1 += y; s2 = fmaf(y,y,s2);
    }
  }
  rs1[tid]=s1; rs2[tid]=s2;
  __syncthreads();
  if(tid<Cout){
    float t1=rs1[tid], t2=rs2[tid];
    for(int p2=1;p2<npt;p2++){ t1+=rs1[tid+p2*Cout]; t2+=rs2[tid+p2*Cout]; }
    const int slot = blockIdx.y*16 + blockIdx.x;
    epart[(size_t)slot*512 + tid]       = t1;
    epart[(size_t)slot*512 + 256 + tid] = t2;
  }
}

__global__ void k_bnfin_edge(const float* __restrict__ epart,
    const float* __restrict__ g, const float* __restrict__ bbias, float inv_cnt,
    float* __restrict__ sc, float* __restrict__ sh, int C){
  int o = threadIdx.x;
  if(o<C){
    float s1=0.f, s2=0.f;
    for(int s=0;s<256;s++){
      s1 += epart[(size_t)s*512 + o];
      s2 += epart[(size_t)s*512 + 256 + o];
    }
    float mean = s1*inv_cnt;
    float var  = s2*inv_cnt - mean*mean;
    float sca = g[o]*rsqrtf(var+EPSF);
    sc[o]=sca; sh[o]=fmaf(-mean,sca,bbias[o]);
  }
}

__global__ void k_eapply(const float* __restrict__ u, const float* __restrict__ v,
    const int* __restrict__ idx, const float* __restrict__ para, int poff,
    const float* __restrict__ sc, const float* __restrict__ sh,
    float* __restrict__ out, int Cout){
  const int n = blockIdx.x*256+threadIdx.x;
  const int o = blockIdx.y, b = blockIdx.z;
  const float p0=para[poff], p1=para[poff+1];
  const float* ub = u + ((size_t)b*Cout+o)*1024;
  float un=ub[n], vn=v[((size_t)b*Cout+o)*1024+n];
  float base = fmaf(p1,vn,-p0*un);
  float s=sc[o], t=sh[o];
  const int* ip = idx + ((size_t)b*1024+n)*10;
  float m=-3.4e38f;
  #pragma unroll
  for(int k2=0;k2<10;k2++){
    int j=ip[k2];
    float y = fmaf(p0, ub[j], base);
    y = fmaf(y,s,t);
    y = (y>0.f)? y : 0.2f*y;
    m = fmaxf(m,y);
  }
  out[(size_t)b*655360 + (size_t)o*1024 + n] = m;
}

__global__ void k_cstats(const float* __restrict__ y5, float* __restrict__ cpart){
  __shared__ float r1[256], r2[256];
  const int o=blockIdx.x, b=blockIdx.y, tid=threadIdx.x;
  const float* yp = y5 + ((size_t)b*1024+o)*1024;
  float s1=0.f,s2=0.f;
  for(int n=tid;n<1024;n+=256){ float y=yp[n]; s1+=y; s2=fmaf(y,y,s2); }
  r1[tid]=s1; r2[tid]=s2; __syncthreads();
  for(int st=128; st>0; st>>=1){ if(tid<st){ r1[tid]+=r1[tid+st]; r2[tid]+=r2[tid+st]; } __syncthreads(); }
  if(tid==0){ cpart[(size_t)b*2048 + o] = r1[0]; cpart[(size_t)b*2048 + 1024 + o] = r2[0]; }
}

__global__ void k_bnfin5(const float* __restrict__ cpart,
    const float* __restrict__ g, const float* __restrict__ bbias, float inv_cnt,
    float* __restrict__ sc, float* __restrict__ sh){
  int o = blockIdx.x*256+threadIdx.x;
  float s1=0.f, s2=0.f;
  #pragma unroll
  for(int b=0;b<16;b++){
    s1 += cpart[(size_t)b*2048 + o];
    s2 += cpart[(size_t)b*2048 + 1024 + o];
  }
  float mean = s1*inv_cnt;
  float var  = s2*inv_cnt - mean*mean;
  float sca = g[o]*rsqrtf(var+EPSF);
  sc[o]=sca; sh[o]=fmaf(-mean,sca,bbias[o]);
}

__global__ void k_pool(const float* __restrict__ y5, const float* __restrict__ sc,
    const float* __restrict__ sh, float* __restrict__ p){
  __shared__ float r1[256], r2[256];
  const int o=blockIdx.x, b=blockIdx.y, tid=threadIdx.x;
  const float* yp = y5 + ((size_t)b*1024+o)*1024;
  float s=sc[o], t=sh[o];
  float mx=-3.4e38f, sm=0.f;
  for(int n=tid;n<1024;n+=256){
    float y=fmaf(yp[n],s,t);
    y=(y>0.f)?y:0.2f*y;
    mx=fmaxf(mx,y); sm+=y;
  }
  r1[tid]=mx; r2[tid]=sm; __syncthreads();
  for(int st=128; st>0; st>>=1){ if(tid<st){ r1[tid]=fmaxf(r1[tid],r1[tid+st]); r2[tid]+=r2[tid+st]; } __syncthreads(); }
  if(tid==0){ p[(size_t)b*2048+o]=r1[0]; p[(size_t)b*2048+1024+o]=r2[0]*(1.f/1024.f); }
}

__global__ void k_lin(const float* __restrict__ In, const float* __restrict__ W,
    const float* __restrict__ g, const float* __restrict__ bbias,
    float* __restrict__ out, int Cin, int Jtot){
  __shared__ float zb[16];
  __shared__ float sscale, sshift;
  const int j=blockIdx.x, tid=threadIdx.x;
  const int bi=tid>>4, part=tid&15;
  const int chunk=Cin>>4;
  const float* ip = In + (size_t)bi*Cin + part*chunk;
  const float* wp = W + (size_t)j*Cin + part*chunk;
  float s=0.f;
  for(int i=0;i<chunk;i++) s=fmaf(ip[i],wp[i],s);
  #pragma unroll
  for(int off=8;off>=1;off>>=1) s += __shfl_xor(s,off,16);
  if(part==0) zb[bi]=s;
  __syncthreads();
  if(tid==0){
    float m=0.f;
    #pragma unroll
    for(int i=0;i<16;i++) m+=zb[i];
    m*=0.0625f;
    float vv=0.f;
    #pragma unroll
    for(int i=0;i<16;i++){ float d=zb[i]-m; vv=fmaf(d,d,vv); }
    vv*=0.0625f;
    float sc=g[j]*rsqrtf(vv+EPSF);
    sscale=sc; sshift=fmaf(-m,sc,bbias[j]);
  }
  __syncthreads();
  if(tid<16){
    float y=fmaf(zb[tid],sscale,sshift);
    y=(y>0.f)?y:0.2f*y;
    out[(size_t)tid*Jtot + j]=y;
  }
}

extern "C" void kernel_launch(void* const* d_in, const int* in_sizes, int n_in,
                              void* d_out, int out_size, void* d_ws, size_t ws_size,
                              hipStream_t stream){
  const float* disc=(const float*)d_in[0];
  const float* x   =(const float*)d_in[1];
  const float* pos_w=(const float*)d_in[3];
  const float* pos_b=(const float*)d_in[4];
  const float* para=(const float*)d_in[5];
  const float* w1=(const float*)d_in[6];
  const float* g1=(const float*)d_in[7];
  const float* b1=(const float*)d_in[8];
  const float* r1w=(const float*)d_in[9];
  const float* w2=(const float*)d_in[10];
  const float* g2=(const float*)d_in[11];
  const float* b2=(const float*)d_in[12];
  const float* w3=(const float*)d_in[13];
  const float* g3=(const float*)d_in[14];
  const float* b3=(const float*)d_in[15];
  const float* r3w=(const float*)d_in[16];
  const float* w4=(const float*)d_in[17];
  const float* g4=(const float*)d_in[18];
  const float* b4=(const float*)d_in[19];
  const float* w5=(const float*)d_in[20];
  const float* g5=(const float*)d_in[21];
  const float* b5=(const float*)d_in[22];
  const float* l1w=(const float*)d_in[23];
  const float* g6=(const float*)d_in[24];
  const float* b6=(const float*)d_in[25];
  const float* l2w=(const float*)d_in[26];
  const float* g7=(const float*)d_in[27];
  const float* b7=(const float*)d_in[28];

  float* ws=(float*)d_ws;
  float* x0 = ws;                     // 2,097,152
  float* xc = x0 + 2097152;           // 10,485,760
  float* yb = xc + 10485760;          // 20,971,520 (16*1024*10*128)
  float* u  = yb;                     // edge4 only
  float* v  = yb + 4194304;           // edge4 only
  float* y5 = yb;                     // conv5 out (aliases, after edges)
  float* tail = yb + 20971520;
  float* sq = tail;                   // 16,384
  float* pv = sq + 16384;             // 393,216
  int*   pi = (int*)(pv + 393216);    // 393,216
  int*   idx= pi + 393216;            // 163,840
  float* epart = (float*)(idx + 163840); // 131,072
  float* cpart = epart + 131072;      // 32,768
  float* scsh  = cpart + 32768;       // 4,096
  float* p  = scsh + 4096;            // 32,768
  float* h1 = p + 32768;              // 8,192

  k_pos<<<dim3(4,128,16),256,0,stream>>>(x,disc,pos_w,pos_b,x0);

  auto knn=[&](const float* xin, int xcoff, int xbstr){
    k_sqnorm<<<dim3(4,16),256,0,stream>>>(xin,xcoff,xbstr,sq);
    k_knn<<<dim3(16,2,16),256,0,stream>>>(xin,xcoff,xbstr,sq,pv,pi);
    k_knn_merge<<<dim3(64),256,0,stream>>>(pv,pi,idx);
  };

  auto edge_exact=[&](const float* xin, int xcoff, int xbstr,
                      const float* w, const float* resw,
                      const float* g, const float* bbias, int poff, int cbase, int blk){
    knn(xin,xcoff,xbstr);
    k_eexact<<<dim3(512,16),256,0,stream>>>(xin,xcoff,xbstr, idx, w, para,poff, yb);
    float* mv = scsh + blk*512;
    k_ystats_sum<<<dim3(16,16),256,0,stream>>>(yb, epart);
    k_bnfin_mean<<<1,256,0,stream>>>(epart, mv);
    k_ystats_var<<<dim3(16,16),256,0,stream>>>(yb, mv, epart);
    k_bnfin_var<<<1,256,0,stream>>>(epart, mv);
    if(resw)
      k_eapply_res<<<dim3(512,16),256,0,stream>>>(xin,xcoff,xbstr, idx, resw, para,poff,
                                                  yb, mv, g,bbias, xc + (size_t)cbase*1024);
    else
      k_yapply<<<dim3(512,16),256,0,stream>>>(yb, mv, g,bbias, xc + (size_t)cbase*1024);
  };

  edge_exact(x0,   0, 131072, w1, r1w,    g1, b1, 0,   0, 0);
  edge_exact(xc,   0, 655360, w2, nullptr,g2, b2, 4, 128, 1);
  edge_exact(xc, 128, 655360, w3, r3w,    g3, b3, 8, 256, 2);

  // edge 4 (smooth consumers only): fast factored path
  {
    knn(xc, 256, 655360);
    dim3 gg(16,4,16);
    k_gemm<<<gg,256,0,stream>>>(w4,256,0,  xc,655360,256, u, 262144, 128);
    k_gemm<<<gg,256,0,stream>>>(w4,256,128,xc,655360,256, v, 262144, 128);
    float* scb = scsh + 3*512;
    float* shb = scb + 256;
    k_estats<<<dim3(16,16),256,0,stream>>>(u,v,idx,para,12,epart,256);
    k_bnfin_edge<<<1,256,0,stream>>>(epart,g4,b4,1.f/163840.f,scb,shb,256);
    k_eapply<<<dim3(4,256,16),256,0,stream>>>(u,v,idx,para,12,scb,shb,
                                              xc + (size_t)384*1024, 256);
  }

  float* sc5 = scsh + 2048;
  float* sh5 = sc5 + 1024;
  k_gemm<<<dim3(16,16,16),256,0,stream>>>(w5,640,0, xc,655360,0, y5,1048576, 640);
  k_cstats<<<dim3(1024,16),256,0,stream>>>(y5,cpart);
  k_bnfin5<<<dim3(4),256,0,stream>>>(cpart,g5,b5,1.f/16384.f,sc5,sh5);
  k_pool<<<dim3(1024,16),256,0,stream>>>(y5,sc5,sh5,p);
  k_lin<<<512,256,0,stream>>>(p,l1w,g6,b6,h1,2048,512);
  k_lin<<<256,256,0,stream>>>(h1,l2w,g7,b7,(float*)d_out,512,256);
}